// Round 3
// baseline (318.881 us; speedup 1.0000x reference)
//
#include <hip/hip_runtime.h>

// Problem constants
#define D_MODEL 1024
#define NHEADS  16
#define HDIM    64
#define BATCH   2
#define SEQ     2048
#define M_TOK   (BATCH * SEQ)   // 4096

typedef unsigned short u16;
typedef unsigned int   u32;
typedef __attribute__((ext_vector_type(8))) short  short8;
typedef __attribute__((ext_vector_type(4))) float  floatx4;
typedef __attribute__((ext_vector_type(2))) u32    u32x2;

#define GLOBAL_AS __attribute__((address_space(1)))
#define LDS_AS    __attribute__((address_space(3)))

// async global->LDS, 16B per lane; LDS dst = wave-uniform base + lane*16 (m97 pattern)
static __device__ __forceinline__ void gload_lds16(const u16* g, u16* l) {
    __builtin_amdgcn_global_load_lds((const GLOBAL_AS u32*)g, (LDS_AS u32*)l, 16, 0, 0);
}

static __device__ __forceinline__ u16 f2bf(float f) {
    union { float f; u32 i; } v; v.f = f;
    u32 x = v.i;
    return (u16)((x + 0x7fffu + ((x >> 16) & 1u)) >> 16);
}

// pack 2 f32 -> 2 bf16 in one u32 (lo=a, hi=b), single VALU op
static __device__ __forceinline__ u32 cvtpk(float a, float b) {
    u32 r;
    asm("v_cvt_pk_bf16_f32 %0, %1, %2" : "=v"(r) : "v"(a), "v"(b));
    return r;
}

// load 8 fp32, RNE to bf16, pack as short8
static __device__ __forceinline__ short8 ld8_cvt(const float* __restrict__ p) {
    float4 f0 = *(const float4*)(p);
    float4 f1 = *(const float4*)(p + 4);
    short8 r;
    r[0] = (short)f2bf(f0.x); r[1] = (short)f2bf(f0.y);
    r[2] = (short)f2bf(f0.z); r[3] = (short)f2bf(f0.w);
    r[4] = (short)f2bf(f1.x); r[5] = (short)f2bf(f1.y);
    r[6] = (short)f2bf(f1.z); r[7] = (short)f2bf(f1.w);
    return r;
}

// ---------------------------------------------------------------------------
__global__ __launch_bounds__(256) void zerofill_k(float* __restrict__ out, int n) {
    int i = blockIdx.x * 256 + threadIdx.x;
    if (i < n) out[i] = 0.f;
}

// Fused prep: z<4 -> transpose+convert weight z; z==4 -> convert x to bf16.
// grid (32, 32, 5), block (32, 32)
__global__ __launch_bounds__(1024) void prep_k(const float* __restrict__ x,
                                               const float* __restrict__ W0,
                                               const float* __restrict__ W1,
                                               const float* __restrict__ W2,
                                               const float* __restrict__ W3,
                                               u16* __restrict__ WtBase,
                                               u16* __restrict__ Xb) {
    int z = blockIdx.z;
    if (z == 4) {
        int blk = blockIdx.y * 32 + blockIdx.x;          // 0..1023
        int t   = threadIdx.y * 32 + threadIdx.x;        // 0..1023
        size_t i0 = ((size_t)blk * 1024 + t) * 4;        // 4 floats/thread
        float4 f = *(const float4*)(x + i0);
        u32 lo = (u32)f2bf(f.x) | ((u32)f2bf(f.y) << 16);
        u32 hi = (u32)f2bf(f.z) | ((u32)f2bf(f.w) << 16);
        *(u32*)(Xb + i0)     = lo;
        *(u32*)(Xb + i0 + 2) = hi;
        return;
    }
    const float* W = (z == 0) ? W0 : (z == 1) ? W1 : (z == 2) ? W2 : W3;
    u16* Wt = WtBase + (size_t)z * 1024 * 1024;
    __shared__ u16 tile[32][33];
    int tx = threadIdx.x, ty = threadIdx.y;
    int bx = blockIdx.x * 32, by = blockIdx.y * 32;
    tile[ty][tx] = f2bf(W[(size_t)(by + ty) * 1024 + bx + tx]);
    __syncthreads();
    Wt[(size_t)(bx + ty) * 1024 + by + tx] = tile[tx][ty];
}

// ---------------------------------------------------------------------------
// GEMM core (m97 structure): C[BMxN tile] = A(bf16) @ Bt(bf16)^T, + bias, *scale.
// Block tile: (MI*32) x 128, BK=32, global_load_lds width-16 staging.
// MODE 0: C[row*1024+col] fp32(OUTF32) or bf16
// MODE 1: head-split [B,H,S,64] bf16
// MODE 2: head-split TRANSPOSED [B,H,64,S] bf16 via LDS-transposed coalesced
//         epilogue (MI must be 4)
// smem: >= max(MI*32*32 + 128*32, 64*136) u16
// ---------------------------------------------------------------------------
template <int MODE, int OUTF32, int MI>
static __device__ __forceinline__ void gemm_core(u16* __restrict__ smem,
                                                 const u16* __restrict__ A,
                                                 const u16* __restrict__ Bt,
                                                 const float* __restrict__ bias,
                                                 float scale,
                                                 void* __restrict__ C,
                                                 int m0, int n0) {
    u16* As = smem;                  // (MI*32) x 32
    u16* Bs = smem + MI * 32 * 32;   // 128 x 32
    int tid  = threadIdx.x;
    int wave = tid >> 6, lane = tid & 63;
    int quad = lane >> 4, l15 = lane & 15;
    int wm = (wave & 1) * (MI * 16);
    int wn = (wave >> 1) * 64;

    floatx4 acc[MI][4] = {};

    for (int k0 = 0; k0 < 1024; k0 += 32) {
#pragma unroll
        for (int t = 0; t < MI / 2; ++t) {
            int a = t * 256 + tid;
            gload_lds16(A + (size_t)(m0 + (a >> 2)) * 1024 + k0 + (a & 3) * 8, As + (size_t)a * 8);
        }
#pragma unroll
        for (int t = 0; t < 2; ++t) {
            int cb = t * 256 + tid;
            gload_lds16(Bt + (size_t)(n0 + (cb >> 2)) * 1024 + k0 + (cb & 3) * 8, Bs + (size_t)cb * 8);
        }
        __syncthreads();   // drains vmcnt before barrier

        short8 af[MI], bfr[4];
#pragma unroll
        for (int i = 0; i < MI; ++i)
            af[i] = *(const short8*)(As + (wm + i * 16 + l15) * 32 + quad * 8);
#pragma unroll
        for (int j = 0; j < 4; ++j)
            bfr[j] = *(const short8*)(Bs + (wn + j * 16 + l15) * 32 + quad * 8);
#pragma unroll
        for (int i = 0; i < MI; ++i)
#pragma unroll
            for (int j = 0; j < 4; ++j)
                acc[i][j] = __builtin_amdgcn_mfma_f32_16x16x32_bf16(af[i], bfr[j], acc[i][j], 0, 0, 0);
        __syncthreads();
    }

    if constexpr (MODE == 2) {
        // Transposed epilogue: two 64-col passes through LDS T[64][136], then
        // coalesced 256B row-bursts to V^T [B,H,64,S].
        u16* T = smem;   // 64*136 u16, aliases As/Bs (dead now)
        int bb = m0 >> 11;
#pragma unroll
        for (int p = 0; p < 2; ++p) {
            if (p) __syncthreads();          // prior copy reads complete
            if ((wave >> 1) == p) {
#pragma unroll
                for (int j = 0; j < 4; ++j) {
                    int dcol = j * 16 + l15;                 // 0..63 within pass
                    float bv = bias[n0 + p * 64 + dcol];
#pragma unroll
                    for (int i = 0; i < MI; ++i) {
#pragma unroll
                        for (int rr = 0; rr < 2; ++rr) {
                            int srow = wm + i * 16 + quad * 4 + rr * 2;
                            u16 lo = f2bf((acc[i][j][rr * 2]     + bv) * scale);
                            u16 hi = f2bf((acc[i][j][rr * 2 + 1] + bv) * scale);
                            *(u32*)(T + dcol * 136 + srow) = (u32)lo | ((u32)hi << 16);
                        }
                    }
                }
            }
            __syncthreads();                 // T visible to all
            int d  = tid >> 2;               // 0..63
            int sc = (tid & 3) * 32;
            int col = n0 + p * 64 + d;
            int h = col >> 6, dd = col & 63;
            int s0 = (m0 & 2047) + sc;
            size_t gbase = (((size_t)bb * NHEADS + h) * HDIM + dd) * SEQ + s0;
#pragma unroll
            for (int c = 0; c < 4; ++c)
                *(short8*)((u16*)C + gbase + c * 8) = *(const short8*)(T + d * 136 + sc + c * 8);
        }
        return;
    }

    // epilogue (MODE 0/1): C/D layout col=lane&15, row=quad*4+reg
#pragma unroll
    for (int j = 0; j < 4; ++j) {
        int col = n0 + wn + j * 16 + l15;
        float bv = bias[col];
#pragma unroll
        for (int i = 0; i < MI; ++i) {
#pragma unroll
            for (int r = 0; r < 4; ++r) {
                int row = m0 + wm + i * 16 + quad * 4 + r;
                float v = (acc[i][j][r] + bv) * scale;
                size_t idx;
                if (MODE == 0) {
                    idx = (size_t)row * 1024 + col;
                } else {  // MODE 1: [B,H,S,64]
                    int b = row >> 11, s = row & 2047;
                    int h = col >> 6,  d = col & 63;
                    idx = (((size_t)b * NHEADS + h) * SEQ + s) * HDIM + d;
                }
                if constexpr (OUTF32) ((float*)C)[idx] = v;
                else                  ((u16*)C)[idx] = f2bf(v);
            }
        }
    }
}

// QKV fused: grid (8, 32, 3). Q pre-scaled by log2(e)/8; V written transposed.
__global__ __launch_bounds__(256) void gemm_qkv(const u16* __restrict__ X,
                                                const u16* __restrict__ WtBase,
                                                const float* __restrict__ bq,
                                                const float* __restrict__ bk,
                                                const float* __restrict__ bv,
                                                u16* __restrict__ OutBase) {
    __shared__ __align__(16) u16 smem[8704];   // max(As+Bs=8192, T=64*136=8704)
    int z = blockIdx.z;
    const u16* Bt     = WtBase + (size_t)z * 1024 * 1024;
    const float* bias = (z == 0) ? bq : (z == 1) ? bk : bv;
    u16* C            = OutBase + (size_t)z * (size_t)M_TOK * 1024;
    if (z == 2)
        gemm_core<2, 0, 4>(smem, X, Bt, bias, 1.0f, C, blockIdx.y * 128, blockIdx.x * 128);
    else if (z == 0)
        gemm_core<1, 0, 4>(smem, X, Bt, bias, 0.18033688011112042f /* log2(e)/8 */, C,
                           blockIdx.y * 128, blockIdx.x * 128);
    else
        gemm_core<1, 0, 4>(smem, X, Bt, bias, 1.0f, C, blockIdx.y * 128, blockIdx.x * 128);
}

// Output projection: grid (8, 64), 64x128 tiles -> 512 blocks (2/CU). fp32 out.
__global__ __launch_bounds__(256) void gemm_out(const u16* __restrict__ A,
                                                const u16* __restrict__ Bt,
                                                const float* __restrict__ bias,
                                                float* __restrict__ C) {
    __shared__ __align__(16) u16 smem[6144];   // As 64x32 + Bs 128x32
    gemm_core<0, 1, 2>(smem, A, Bt, bias, 1.0f, C, blockIdx.y * 64, blockIdx.x * 128);
}

// ---------------------------------------------------------------------------
// Flash attention v8. grid (SEQ/128, BATCH*NHEADS), 512 threads (8 waves).
// R2 post-mortem: v7 per-wave changes were neutral at fixed residency ->
// stall-bound, and OccupancyPercent 27% (~8.8/32 waves, ~2.2 of 4 possible
// blocks) says the CU never holds enough independent waves to hide the
// per-iter latency chain. v8 merges 2 blocks into one 8-wave block:
//   grid 512 blocks = EXACTLY 2/CU, all resident from t=0 (LDS 43KB*2=86KB
//   <= 160KB; VGPR 80 -> 6 waves/SIMD >= 4 needed). 16 waves/CU guaranteed,
//   no dispatch rounds, no tail imbalance.
// Per-wave inner loop is byte-identical to v7 (proven): swapped QK^T,
// chunked P via cvt_pk + ds_write_b64, V dbuf DMA w/ XOR-16 swizzle,
// K register prefetch, setprio on MFMA clusters.
// __launch_bounds__(512,3): VGPR cap ~170 (usage 80, no spill risk).
// ---------------------------------------------------------------------------
#define PST2 40
__global__ __launch_bounds__(512, 3) void attn_k(const u16* __restrict__ Q,
                                                 const u16* __restrict__ K,
                                                 const u16* __restrict__ Vt_g,
                                                 u16* __restrict__ O) {
    __shared__ __align__(16) u16 Vt[2][64 * 128];   // swizzled granules, 2x16KB
    __shared__ __align__(16) u16 Pl[8][16 * PST2];  // per-wave P chunk, 10240 B

    int tid  = threadIdx.x;
    int wave = tid >> 6, lane = tid & 63;
    int quad = lane >> 4, l15 = lane & 15;
    int bh = blockIdx.y;
    int b = bh >> 4, h = bh & 15;
    const u16* Qb = Q    + (size_t)bh * SEQ * HDIM;
    const u16* Kb = K    + (size_t)bh * SEQ * HDIM;
    const u16* Vb = Vt_g + (size_t)bh * HDIM * SEQ;   // [d][s]
    int q0 = blockIdx.x * 128 + wave * 16;

    // Q A/B-frags (pre-scaled): [m=l15][k=quad*8+j]
    short8 qf0 = *(const short8*)(Qb + (size_t)(q0 + l15) * 64 + quad * 8);
    short8 qf1 = *(const short8*)(Qb + (size_t)(q0 + l15) * 64 + 32 + quad * 8);

    floatx4 o[4] = {};
    float lrow = 0.f;   // partial row sum for q = q0 + l15 (this lane's kv share)

    // K frag prefetch registers (one kv-tile ahead)
    short8 kf0[8], kf1[8];
#pragma unroll
    for (int j = 0; j < 8; ++j) {
        const u16* kp = Kb + (size_t)(j * 16 + l15) * 64 + quad * 8;
        kf0[j] = *(const short8*)kp;
        kf1[j] = *(const short8*)(kp + 32);
    }

    // V DMA for tile 0 into buffer 0 (1024 granules / 512 threads = 2 rounds)
    {
        u16* dst = Vt[0];
#pragma unroll
        for (int rnd = 0; rnd < 2; ++rnd) {
            int g = rnd * 512 + tid;
            int row = g >> 4, cgp = g & 15;
            int real = cgp ^ (row & 15);
            gload_lds16(Vb + (size_t)row * SEQ + real * 8, dst + (size_t)g * 8);
        }
    }

    for (int it = 0; it < SEQ / 128; ++it) {
        int kv0 = it * 128;
        __syncthreads();   // drains DMA(it) [issued one iter ago] + prev K prefetch

        // --- issue DMA(it+1) into the other buffer ---
        if (it + 1 < SEQ / 128) {
            u16* dst = Vt[(it + 1) & 1];
#pragma unroll
            for (int rnd = 0; rnd < 2; ++rnd) {
                int g = rnd * 512 + tid;
                int row = g >> 4, cgp = g & 15;
                int real = cgp ^ (row & 15);
                gload_lds16(Vb + (size_t)row * SEQ + kv0 + 128 + real * 8,
                            dst + (size_t)g * 8);
            }
        }

        // --- S^T = K @ Q^T from prefetched registers (swapped operands) ---
        // s[j] layout: col=l15 = q, row=quad*4+r = kv within j-block
        floatx4 s[8];
        __builtin_amdgcn_s_setprio(1);
#pragma unroll
        for (int j = 0; j < 8; ++j) {
            floatx4 a = {};
            a = __builtin_amdgcn_mfma_f32_16x16x32_bf16(kf0[j], qf0, a, 0, 0, 0);
            a = __builtin_amdgcn_mfma_f32_16x16x32_bf16(kf1[j], qf1, a, 0, 0, 0);
            s[j] = a;
        }
        __builtin_amdgcn_s_setprio(0);

        // --- prefetch K frags for it+1 (drained free at next barrier) ---
        if (it + 1 < SEQ / 128) {
#pragma unroll
            for (int j = 0; j < 8; ++j) {
                const u16* kp = Kb + (size_t)(kv0 + 128 + j * 16 + l15) * 64 + quad * 8;
                kf0[j] = *(const short8*)kp;
                kf1[j] = *(const short8*)(kp + 32);
            }
        }

        // --- per-32-kv chunk: p = exp2(s), pack+store P, then PV on that chunk ---
        const u16* vb = Vt[it & 1];
#pragma unroll
        for (int kh = 0; kh < 4; ++kh) {
            // produce P chunk kh (kv = kh*32 .. kh*32+31), q = l15
#pragma unroll
            for (int t = 0; t < 2; ++t) {
                int j = kh * 2 + t;
                float p0 = exp2f(s[j][0]), p1 = exp2f(s[j][1]);
                float p2 = exp2f(s[j][2]), p3 = exp2f(s[j][3]);
                lrow += (p0 + p1) + (p2 + p3);
                u32 w0 = cvtpk(p0, p1), w1 = cvtpk(p2, p3);
                // kv' = t*16 + quad*4 + r  (4 contiguous bf16 -> one b64)
                *(u32x2*)(&Pl[wave][l15 * PST2 + t * 16 + quad * 4]) = (u32x2){w0, w1};
            }
            // consume: A-frag P[m=l15=q][k=quad*8+i]
            short8 pf = *(const short8*)(&Pl[wave][l15 * PST2 + quad * 8]);
            __builtin_amdgcn_s_setprio(1);
#pragma unroll
            for (int dj = 0; dj < 4; ++dj) {
                int row = dj * 16 + l15;
                int cg  = kh * 4 + quad;
                short8 vf = *(const short8*)(&vb[(row * 16 + (cg ^ l15)) * 8]);
                o[dj] = __builtin_amdgcn_mfma_f32_16x16x32_bf16(pf, vf, o[dj], 0, 0, 0);
            }
            __builtin_amdgcn_s_setprio(0);
        }
    }

    // --- epilogue: complete row sums across quads, redistribute, store ---
    float tsum = lrow;
    tsum += __shfl_xor(tsum, 16, 64);
    tsum += __shfl_xor(tsum, 32, 64);
    float inv = 1.f / tsum;        // for q row = q0 + l15
#pragma unroll
    for (int r = 0; r < 4; ++r) {
        // o layout: row = quad*4+r = q, col = l15 = d -> need inv of q=quad*4+r
        float invq = __shfl(inv, quad * 4 + r, 16);
        int srow = q0 + quad * 4 + r;
        size_t base = ((size_t)b * SEQ + srow) * D_MODEL + h * HDIM;
#pragma unroll
        for (int dj = 0; dj < 4; ++dj)
            O[base + dj * 16 + l15] = f2bf(o[dj][r] * invq);
    }
}

// ---------------------------------------------------------------------------
extern "C" void kernel_launch(void* const* d_in, const int* in_sizes, int n_in,
                              void* d_out, int out_size, void* d_ws, size_t ws_size,
                              hipStream_t stream) {
    const float* x  = (const float*)d_in[0];
    const float* Wq = (const float*)d_in[1];
    const float* bq = (const float*)d_in[2];
    const float* Wk = (const float*)d_in[3];
    const float* bk = (const float*)d_in[4];
    const float* Wv = (const float*)d_in[5];
    const float* bv = (const float*)d_in[6];
    const float* Wo = (const float*)d_in[7];
    const float* bo = (const float*)d_in[8];
    float* out = (float*)d_out;

    char* ws = (char*)d_ws;
    const size_t WSZ = (size_t)1024 * 1024 * sizeof(u16);   // 2MB per bf16 weight
    const size_t QSZ = (size_t)M_TOK * 1024 * sizeof(u16);  // 8MB per bf16 activation
    const size_t NEED = 4 * WSZ + 4 * QSZ;                  // 40MB

    if (ws_size < NEED) {
        zerofill_k<<<dim3((out_size + 255) / 256), 256, 0, stream>>>(out, out_size);
        return;
    }

    u16* wtq = (u16*)(ws);                       // wt q,k,v,o contiguous
    u16* wto = (u16*)(ws + 3 * WSZ);
    u16* Qw  = (u16*)(ws + 4 * WSZ);             // Q,K [B,H,S,64]; V^T [B,H,64,S]
    u16* Kw  = (u16*)(ws + 4 * WSZ + QSZ);
    u16* Vw  = (u16*)(ws + 4 * WSZ + 2 * QSZ);
    u16* Xb  = (u16*)(ws + 4 * WSZ + 3 * QSZ);   // x bf16; dead after gemm_qkv
    u16* Aw  = Xb;                               // attention output reuses Xb

    prep_k<<<dim3(32, 32, 5), dim3(32, 32), 0, stream>>>(x, Wq, Wk, Wv, Wo, wtq, Xb);

    gemm_qkv<<<dim3(8, 32, 3), 256, 0, stream>>>(Xb, wtq, bq, bk, bv, Qw);
    attn_k<<<dim3(SEQ / 128, BATCH * NHEADS), 512, 0, stream>>>(Qw, Kw, Vw, Aw);
    gemm_out<<<dim3(8, 64), 256, 0, stream>>>(Aw, wto, bo, out);
}

// Round 4
// 223.975 us; speedup vs baseline: 1.4237x; 1.4237x over previous
//
#include <hip/hip_runtime.h>

// Problem constants
#define D_MODEL 1024
#define NHEADS  16
#define HDIM    64
#define BATCH   2
#define SEQ     2048
#define M_TOK   (BATCH * SEQ)   // 4096

typedef unsigned short u16;
typedef unsigned int   u32;
typedef __attribute__((ext_vector_type(8))) short  short8;
typedef __attribute__((ext_vector_type(4))) float  floatx4;
typedef __attribute__((ext_vector_type(2))) u32    u32x2;

#define GLOBAL_AS __attribute__((address_space(1)))
#define LDS_AS    __attribute__((address_space(3)))

// async global->LDS, 16B per lane; LDS dst = wave-uniform base + lane*16 (m97 pattern)
static __device__ __forceinline__ void gload_lds16(const u16* g, u16* l) {
    __builtin_amdgcn_global_load_lds((const GLOBAL_AS u32*)g, (LDS_AS u32*)l, 16, 0, 0);
}

static __device__ __forceinline__ u16 f2bf(float f) {
    union { float f; u32 i; } v; v.f = f;
    u32 x = v.i;
    return (u16)((x + 0x7fffu + ((x >> 16) & 1u)) >> 16);
}

// pack 2 f32 -> 2 bf16 in one u32 (lo=a, hi=b), single VALU op
static __device__ __forceinline__ u32 cvtpk(float a, float b) {
    u32 r;
    asm("v_cvt_pk_bf16_f32 %0, %1, %2" : "=v"(r) : "v"(a), "v"(b));
    return r;
}

// load 8 fp32, RNE to bf16, pack as short8
static __device__ __forceinline__ short8 ld8_cvt(const float* __restrict__ p) {
    float4 f0 = *(const float4*)(p);
    float4 f1 = *(const float4*)(p + 4);
    short8 r;
    r[0] = (short)f2bf(f0.x); r[1] = (short)f2bf(f0.y);
    r[2] = (short)f2bf(f0.z); r[3] = (short)f2bf(f0.w);
    r[4] = (short)f2bf(f1.x); r[5] = (short)f2bf(f1.y);
    r[6] = (short)f2bf(f1.z); r[7] = (short)f2bf(f1.w);
    return r;
}

// ---------------------------------------------------------------------------
__global__ __launch_bounds__(256) void zerofill_k(float* __restrict__ out, int n) {
    int i = blockIdx.x * 256 + threadIdx.x;
    if (i < n) out[i] = 0.f;
}

// Fused prep: z<4 -> transpose+convert weight z; z==4 -> convert x to bf16.
// grid (32, 32, 5), block (32, 32)
__global__ __launch_bounds__(1024) void prep_k(const float* __restrict__ x,
                                               const float* __restrict__ W0,
                                               const float* __restrict__ W1,
                                               const float* __restrict__ W2,
                                               const float* __restrict__ W3,
                                               u16* __restrict__ WtBase,
                                               u16* __restrict__ Xb) {
    int z = blockIdx.z;
    if (z == 4) {
        int blk = blockIdx.y * 32 + blockIdx.x;          // 0..1023
        int t   = threadIdx.y * 32 + threadIdx.x;        // 0..1023
        size_t i0 = ((size_t)blk * 1024 + t) * 4;        // 4 floats/thread
        float4 f = *(const float4*)(x + i0);
        u32 lo = (u32)f2bf(f.x) | ((u32)f2bf(f.y) << 16);
        u32 hi = (u32)f2bf(f.z) | ((u32)f2bf(f.w) << 16);
        *(u32*)(Xb + i0)     = lo;
        *(u32*)(Xb + i0 + 2) = hi;
        return;
    }
    const float* W = (z == 0) ? W0 : (z == 1) ? W1 : (z == 2) ? W2 : W3;
    u16* Wt = WtBase + (size_t)z * 1024 * 1024;
    __shared__ u16 tile[32][33];
    int tx = threadIdx.x, ty = threadIdx.y;
    int bx = blockIdx.x * 32, by = blockIdx.y * 32;
    tile[ty][tx] = f2bf(W[(size_t)(by + ty) * 1024 + bx + tx]);
    __syncthreads();
    Wt[(size_t)(bx + ty) * 1024 + by + tx] = tile[tx][ty];
}

// ---------------------------------------------------------------------------
// GEMM core (m97 structure): C[BMxN tile] = A(bf16) @ Bt(bf16)^T, + bias, *scale.
// Block tile: (MI*32) x 128, BK=32, global_load_lds width-16 staging.
// MODE 0: C[row*1024+col] fp32(OUTF32) or bf16
// MODE 1: head-split [B,H,S,64] bf16
// MODE 2: head-split TRANSPOSED [B,H,64,S] bf16 via LDS-transposed coalesced
//         epilogue (MI must be 4)
// smem: >= max(MI*32*32 + 128*32, 64*136) u16
// ---------------------------------------------------------------------------
template <int MODE, int OUTF32, int MI>
static __device__ __forceinline__ void gemm_core(u16* __restrict__ smem,
                                                 const u16* __restrict__ A,
                                                 const u16* __restrict__ Bt,
                                                 const float* __restrict__ bias,
                                                 float scale,
                                                 void* __restrict__ C,
                                                 int m0, int n0) {
    u16* As = smem;                  // (MI*32) x 32
    u16* Bs = smem + MI * 32 * 32;   // 128 x 32
    int tid  = threadIdx.x;
    int wave = tid >> 6, lane = tid & 63;
    int quad = lane >> 4, l15 = lane & 15;
    int wm = (wave & 1) * (MI * 16);
    int wn = (wave >> 1) * 64;

    floatx4 acc[MI][4] = {};

    for (int k0 = 0; k0 < 1024; k0 += 32) {
#pragma unroll
        for (int t = 0; t < MI / 2; ++t) {
            int a = t * 256 + tid;
            gload_lds16(A + (size_t)(m0 + (a >> 2)) * 1024 + k0 + (a & 3) * 8, As + (size_t)a * 8);
        }
#pragma unroll
        for (int t = 0; t < 2; ++t) {
            int cb = t * 256 + tid;
            gload_lds16(Bt + (size_t)(n0 + (cb >> 2)) * 1024 + k0 + (cb & 3) * 8, Bs + (size_t)cb * 8);
        }
        __syncthreads();   // drains vmcnt before barrier

        short8 af[MI], bfr[4];
#pragma unroll
        for (int i = 0; i < MI; ++i)
            af[i] = *(const short8*)(As + (wm + i * 16 + l15) * 32 + quad * 8);
#pragma unroll
        for (int j = 0; j < 4; ++j)
            bfr[j] = *(const short8*)(Bs + (wn + j * 16 + l15) * 32 + quad * 8);
#pragma unroll
        for (int i = 0; i < MI; ++i)
#pragma unroll
            for (int j = 0; j < 4; ++j)
                acc[i][j] = __builtin_amdgcn_mfma_f32_16x16x32_bf16(af[i], bfr[j], acc[i][j], 0, 0, 0);
        __syncthreads();
    }

    if constexpr (MODE == 2) {
        // Transposed epilogue: two 64-col passes through LDS T[64][136], then
        // coalesced 256B row-bursts to V^T [B,H,64,S].
        u16* T = smem;   // 64*136 u16, aliases As/Bs (dead now)
        int bb = m0 >> 11;
#pragma unroll
        for (int p = 0; p < 2; ++p) {
            if (p) __syncthreads();          // prior copy reads complete
            if ((wave >> 1) == p) {
#pragma unroll
                for (int j = 0; j < 4; ++j) {
                    int dcol = j * 16 + l15;                 // 0..63 within pass
                    float bv = bias[n0 + p * 64 + dcol];
#pragma unroll
                    for (int i = 0; i < MI; ++i) {
#pragma unroll
                        for (int rr = 0; rr < 2; ++rr) {
                            int srow = wm + i * 16 + quad * 4 + rr * 2;
                            u16 lo = f2bf((acc[i][j][rr * 2]     + bv) * scale);
                            u16 hi = f2bf((acc[i][j][rr * 2 + 1] + bv) * scale);
                            *(u32*)(T + dcol * 136 + srow) = (u32)lo | ((u32)hi << 16);
                        }
                    }
                }
            }
            __syncthreads();                 // T visible to all
            int d  = tid >> 2;               // 0..63
            int sc = (tid & 3) * 32;
            int col = n0 + p * 64 + d;
            int h = col >> 6, dd = col & 63;
            int s0 = (m0 & 2047) + sc;
            size_t gbase = (((size_t)bb * NHEADS + h) * HDIM + dd) * SEQ + s0;
#pragma unroll
            for (int c = 0; c < 4; ++c)
                *(short8*)((u16*)C + gbase + c * 8) = *(const short8*)(T + d * 136 + sc + c * 8);
        }
        return;
    }

    // epilogue (MODE 0/1): C/D layout col=lane&15, row=quad*4+reg
#pragma unroll
    for (int j = 0; j < 4; ++j) {
        int col = n0 + wn + j * 16 + l15;
        float bv = bias[col];
#pragma unroll
        for (int i = 0; i < MI; ++i) {
#pragma unroll
            for (int r = 0; r < 4; ++r) {
                int row = m0 + wm + i * 16 + quad * 4 + r;
                float v = (acc[i][j][r] + bv) * scale;
                size_t idx;
                if (MODE == 0) {
                    idx = (size_t)row * 1024 + col;
                } else {  // MODE 1: [B,H,S,64]
                    int b = row >> 11, s = row & 2047;
                    int h = col >> 6,  d = col & 63;
                    idx = (((size_t)b * NHEADS + h) * SEQ + s) * HDIM + d;
                }
                if constexpr (OUTF32) ((float*)C)[idx] = v;
                else                  ((u16*)C)[idx] = f2bf(v);
            }
        }
    }
}

// QKV fused: grid (8, 32, 3). Q pre-scaled by log2(e)/8; V written transposed.
__global__ __launch_bounds__(256) void gemm_qkv(const u16* __restrict__ X,
                                                const u16* __restrict__ WtBase,
                                                const float* __restrict__ bq,
                                                const float* __restrict__ bk,
                                                const float* __restrict__ bv,
                                                u16* __restrict__ OutBase) {
    __shared__ __align__(16) u16 smem[8704];   // max(As+Bs=8192, T=64*136=8704)
    int z = blockIdx.z;
    const u16* Bt     = WtBase + (size_t)z * 1024 * 1024;
    const float* bias = (z == 0) ? bq : (z == 1) ? bk : bv;
    u16* C            = OutBase + (size_t)z * (size_t)M_TOK * 1024;
    if (z == 2)
        gemm_core<2, 0, 4>(smem, X, Bt, bias, 1.0f, C, blockIdx.y * 128, blockIdx.x * 128);
    else if (z == 0)
        gemm_core<1, 0, 4>(smem, X, Bt, bias, 0.18033688011112042f /* log2(e)/8 */, C,
                           blockIdx.y * 128, blockIdx.x * 128);
    else
        gemm_core<1, 0, 4>(smem, X, Bt, bias, 1.0f, C, blockIdx.y * 128, blockIdx.x * 128);
}

// Output projection: grid (8, 64), 64x128 tiles -> 512 blocks (2/CU). fp32 out.
__global__ __launch_bounds__(256) void gemm_out(const u16* __restrict__ A,
                                                const u16* __restrict__ Bt,
                                                const float* __restrict__ bias,
                                                float* __restrict__ C) {
    __shared__ __align__(16) u16 smem[6144];   // As 64x32 + Bs 128x32
    gemm_core<0, 1, 2>(smem, A, Bt, bias, 1.0f, C, blockIdx.y * 64, blockIdx.x * 128);
}

// ---------------------------------------------------------------------------
// Flash attention v9. grid (SEQ/128, BATCH*NHEADS), 512 threads (8 waves).
// R3 post-mortem: the wall is REDUNDANT K TRAFFIC, not issue cycles or raw
// residency. v7/v8 loaded the full 128x64 K-tile into EVERY wave's registers
// (16KB/wave/iter): v7 = 1.31 GB through L2 @9 TB/s; v8 = 2.36 GB @14 TB/s
// (more waves -> more demand -> slower wall despite higher delivered BW).
// v9 stages K in LDS ONCE per block (like V), double-buffered via
// global_load_lds: 144KB -> 32KB per block-iter, total 0.26 GB.
// - K tile [128][64] has 128B row stride = bank-conflict city; DMA
//   pre-swizzles the GLOBAL source granule (cgp ^ (row&7)) so linear LDS
//   holds swizzled data; frag read applies the same XOR (rule 21).
// - 8-wave block, 512 blocks = exactly 2/CU resident (LDS 75.8KB/block).
// - kf register arrays gone (-64 VGPR).
// Everything else identical to v8: swapped QK^T, chunked P via cvt_pk +
// ds_write_b64, V dbuf DMA w/ XOR-16 swizzle, setprio on MFMA clusters.
// ---------------------------------------------------------------------------
#define PST2 40
__global__ __launch_bounds__(512, 3) void attn_k(const u16* __restrict__ Q,
                                                 const u16* __restrict__ K,
                                                 const u16* __restrict__ Vt_g,
                                                 u16* __restrict__ O) {
    __shared__ __align__(16) u16 Vt[2][64 * 128];   // V^T tile, swizzled granules, 2x16KB
    __shared__ __align__(16) u16 Kt[2][128 * 64];   // K tile, swizzled granules, 2x16KB
    __shared__ __align__(16) u16 Pl[8][16 * PST2];  // per-wave P chunk, 10240 B

    int tid  = threadIdx.x;
    int wave = tid >> 6, lane = tid & 63;
    int quad = lane >> 4, l15 = lane & 15;
    int bh = blockIdx.y;
    int b = bh >> 4, h = bh & 15;
    const u16* Qb = Q    + (size_t)bh * SEQ * HDIM;
    const u16* Kb = K    + (size_t)bh * SEQ * HDIM;
    const u16* Vb = Vt_g + (size_t)bh * HDIM * SEQ;   // [d][s]
    int q0 = blockIdx.x * 128 + wave * 16;

    // Q A/B-frags (pre-scaled): [m=l15][k=quad*8+j]
    short8 qf0 = *(const short8*)(Qb + (size_t)(q0 + l15) * 64 + quad * 8);
    short8 qf1 = *(const short8*)(Qb + (size_t)(q0 + l15) * 64 + 32 + quad * 8);

    floatx4 o[4] = {};
    float lrow = 0.f;   // partial row sum for q = q0 + l15 (this lane's kv share)

    // DMA K+V tile 0 into buffer 0 (each 1024 granules / 512 threads = 2 rounds)
    {
#pragma unroll
        for (int rnd = 0; rnd < 2; ++rnd) {
            int g = rnd * 512 + tid;
            int vrow = g >> 4, vc = g & 15;
            gload_lds16(Vb + (size_t)vrow * SEQ + (vc ^ (vrow & 15)) * 8,
                        Vt[0] + (size_t)g * 8);
            int krow = g >> 3, kc = g & 7;
            gload_lds16(Kb + (size_t)krow * 64 + (kc ^ (krow & 7)) * 8,
                        Kt[0] + (size_t)g * 8);
        }
    }

    for (int it = 0; it < SEQ / 128; ++it) {
        int kv0 = it * 128;
        __syncthreads();   // drains DMA(it) [issued one iter ago]

        // --- issue K+V DMA(it+1) into the other buffer ---
        if (it + 1 < SEQ / 128) {
            u16* vdst = Vt[(it + 1) & 1];
            u16* kdst = Kt[(it + 1) & 1];
#pragma unroll
            for (int rnd = 0; rnd < 2; ++rnd) {
                int g = rnd * 512 + tid;
                int vrow = g >> 4, vc = g & 15;
                gload_lds16(Vb + (size_t)vrow * SEQ + kv0 + 128 + (vc ^ (vrow & 15)) * 8,
                            vdst + (size_t)g * 8);
                int krow = g >> 3, kc = g & 7;
                gload_lds16(Kb + (size_t)(kv0 + 128 + krow) * 64 + (kc ^ (krow & 7)) * 8,
                            kdst + (size_t)g * 8);
            }
        }

        // --- S^T = K @ Q^T, K frags from LDS (swizzled read) ---
        // s[j] layout: col=l15 = q, row=quad*4+r = kv within j-block
        const u16* kb = Kt[it & 1];
        floatx4 s[8];
        __builtin_amdgcn_s_setprio(1);
#pragma unroll
        for (int j = 0; j < 8; ++j) {
            int row = j * 16 + l15;                    // row&7 == l15&7
            const u16* kr = kb + (size_t)row * 64;
            short8 k0 = *(const short8*)(kr + ((quad ^ (l15 & 7)) * 8));
            short8 k1 = *(const short8*)(kr + (((quad + 4) ^ (l15 & 7)) * 8));
            floatx4 a = {};
            a = __builtin_amdgcn_mfma_f32_16x16x32_bf16(k0, qf0, a, 0, 0, 0);
            a = __builtin_amdgcn_mfma_f32_16x16x32_bf16(k1, qf1, a, 0, 0, 0);
            s[j] = a;
        }
        __builtin_amdgcn_s_setprio(0);

        // --- per-32-kv chunk: p = exp2(s), pack+store P, then PV on that chunk ---
        const u16* vb = Vt[it & 1];
#pragma unroll
        for (int kh = 0; kh < 4; ++kh) {
            // produce P chunk kh (kv = kh*32 .. kh*32+31), q = l15
#pragma unroll
            for (int t = 0; t < 2; ++t) {
                int j = kh * 2 + t;
                float p0 = exp2f(s[j][0]), p1 = exp2f(s[j][1]);
                float p2 = exp2f(s[j][2]), p3 = exp2f(s[j][3]);
                lrow += (p0 + p1) + (p2 + p3);
                u32 w0 = cvtpk(p0, p1), w1 = cvtpk(p2, p3);
                // kv' = t*16 + quad*4 + r  (4 contiguous bf16 -> one b64)
                *(u32x2*)(&Pl[wave][l15 * PST2 + t * 16 + quad * 4]) = (u32x2){w0, w1};
            }
            // consume: A-frag P[m=l15=q][k=quad*8+i]
            short8 pf = *(const short8*)(&Pl[wave][l15 * PST2 + quad * 8]);
            __builtin_amdgcn_s_setprio(1);
#pragma unroll
            for (int dj = 0; dj < 4; ++dj) {
                int row = dj * 16 + l15;
                int cg  = kh * 4 + quad;
                short8 vf = *(const short8*)(&vb[(row * 16 + (cg ^ l15)) * 8]);
                o[dj] = __builtin_amdgcn_mfma_f32_16x16x32_bf16(pf, vf, o[dj], 0, 0, 0);
            }
            __builtin_amdgcn_s_setprio(0);
        }
    }

    // --- epilogue: complete row sums across quads, redistribute, store ---
    float tsum = lrow;
    tsum += __shfl_xor(tsum, 16, 64);
    tsum += __shfl_xor(tsum, 32, 64);
    float inv = 1.f / tsum;        // for q row = q0 + l15
#pragma unroll
    for (int r = 0; r < 4; ++r) {
        // o layout: row = quad*4+r = q, col = l15 = d -> need inv of q=quad*4+r
        float invq = __shfl(inv, quad * 4 + r, 16);
        int srow = q0 + quad * 4 + r;
        size_t base = ((size_t)b * SEQ + srow) * D_MODEL + h * HDIM;
#pragma unroll
        for (int dj = 0; dj < 4; ++dj)
            O[base + dj * 16 + l15] = f2bf(o[dj][r] * invq);
    }
}

// ---------------------------------------------------------------------------
extern "C" void kernel_launch(void* const* d_in, const int* in_sizes, int n_in,
                              void* d_out, int out_size, void* d_ws, size_t ws_size,
                              hipStream_t stream) {
    const float* x  = (const float*)d_in[0];
    const float* Wq = (const float*)d_in[1];
    const float* bq = (const float*)d_in[2];
    const float* Wk = (const float*)d_in[3];
    const float* bk = (const float*)d_in[4];
    const float* Wv = (const float*)d_in[5];
    const float* bv = (const float*)d_in[6];
    const float* Wo = (const float*)d_in[7];
    const float* bo = (const float*)d_in[8];
    float* out = (float*)d_out;

    char* ws = (char*)d_ws;
    const size_t WSZ = (size_t)1024 * 1024 * sizeof(u16);   // 2MB per bf16 weight
    const size_t QSZ = (size_t)M_TOK * 1024 * sizeof(u16);  // 8MB per bf16 activation
    const size_t NEED = 4 * WSZ + 4 * QSZ;                  // 40MB

    if (ws_size < NEED) {
        zerofill_k<<<dim3((out_size + 255) / 256), 256, 0, stream>>>(out, out_size);
        return;
    }

    u16* wtq = (u16*)(ws);                       // wt q,k,v,o contiguous
    u16* wto = (u16*)(ws + 3 * WSZ);
    u16* Qw  = (u16*)(ws + 4 * WSZ);             // Q,K [B,H,S,64]; V^T [B,H,64,S]
    u16* Kw  = (u16*)(ws + 4 * WSZ + QSZ);
    u16* Vw  = (u16*)(ws + 4 * WSZ + 2 * QSZ);
    u16* Xb  = (u16*)(ws + 4 * WSZ + 3 * QSZ);   // x bf16; dead after gemm_qkv
    u16* Aw  = Xb;                               // attention output reuses Xb

    prep_k<<<dim3(32, 32, 5), dim3(32, 32), 0, stream>>>(x, Wq, Wk, Wv, Wo, wtq, Xb);

    gemm_qkv<<<dim3(8, 32, 3), 256, 0, stream>>>(Xb, wtq, bq, bk, bv, Qw);
    attn_k<<<dim3(SEQ / 128, BATCH * NHEADS), 512, 0, stream>>>(Qw, Kw, Vw, Aw);
    gemm_out<<<dim3(8, 64), 256, 0, stream>>>(Aw, wto, bo, out);
}

// Round 5
// 203.087 us; speedup vs baseline: 1.5702x; 1.1029x over previous
//
#include <hip/hip_runtime.h>

// Problem constants
#define D_MODEL 1024
#define NHEADS  16
#define HDIM    64
#define BATCH   2
#define SEQ     2048
#define M_TOK   (BATCH * SEQ)   // 4096

typedef unsigned short u16;
typedef unsigned int   u32;
typedef __attribute__((ext_vector_type(8))) short  short8;
typedef __attribute__((ext_vector_type(4))) float  floatx4;
typedef __attribute__((ext_vector_type(2))) u32    u32x2;

#define GLOBAL_AS __attribute__((address_space(1)))
#define LDS_AS    __attribute__((address_space(3)))

// async global->LDS, 16B per lane; LDS dst = wave-uniform base + lane*16 (m97 pattern)
static __device__ __forceinline__ void gload_lds16(const u16* g, u16* l) {
    __builtin_amdgcn_global_load_lds((const GLOBAL_AS u32*)g, (LDS_AS u32*)l, 16, 0, 0);
}

static __device__ __forceinline__ u16 f2bf(float f) {
    union { float f; u32 i; } v; v.f = f;
    u32 x = v.i;
    return (u16)((x + 0x7fffu + ((x >> 16) & 1u)) >> 16);
}

// pack 2 f32 -> 2 bf16 in one u32 (lo=a, hi=b), single VALU op
static __device__ __forceinline__ u32 cvtpk(float a, float b) {
    u32 r;
    asm("v_cvt_pk_bf16_f32 %0, %1, %2" : "=v"(r) : "v"(a), "v"(b));
    return r;
}

// load 8 fp32, RNE to bf16, pack as short8
static __device__ __forceinline__ short8 ld8_cvt(const float* __restrict__ p) {
    float4 f0 = *(const float4*)(p);
    float4 f1 = *(const float4*)(p + 4);
    short8 r;
    r[0] = (short)f2bf(f0.x); r[1] = (short)f2bf(f0.y);
    r[2] = (short)f2bf(f0.z); r[3] = (short)f2bf(f0.w);
    r[4] = (short)f2bf(f1.x); r[5] = (short)f2bf(f1.y);
    r[6] = (short)f2bf(f1.z); r[7] = (short)f2bf(f1.w);
    return r;
}

// ---------------------------------------------------------------------------
__global__ __launch_bounds__(256) void zerofill_k(float* __restrict__ out, int n) {
    int i = blockIdx.x * 256 + threadIdx.x;
    if (i < n) out[i] = 0.f;
}

// Fused prep: z<4 -> transpose+convert weight z; z==4 -> convert x to bf16.
// grid (32, 32, 5), block (32, 32)
__global__ __launch_bounds__(1024) void prep_k(const float* __restrict__ x,
                                               const float* __restrict__ W0,
                                               const float* __restrict__ W1,
                                               const float* __restrict__ W2,
                                               const float* __restrict__ W3,
                                               u16* __restrict__ WtBase,
                                               u16* __restrict__ Xb) {
    int z = blockIdx.z;
    if (z == 4) {
        int blk = blockIdx.y * 32 + blockIdx.x;          // 0..1023
        int t   = threadIdx.y * 32 + threadIdx.x;        // 0..1023
        size_t i0 = ((size_t)blk * 1024 + t) * 4;        // 4 floats/thread
        float4 f = *(const float4*)(x + i0);
        u32 lo = (u32)f2bf(f.x) | ((u32)f2bf(f.y) << 16);
        u32 hi = (u32)f2bf(f.z) | ((u32)f2bf(f.w) << 16);
        *(u32*)(Xb + i0)     = lo;
        *(u32*)(Xb + i0 + 2) = hi;
        return;
    }
    const float* W = (z == 0) ? W0 : (z == 1) ? W1 : (z == 2) ? W2 : W3;
    u16* Wt = WtBase + (size_t)z * 1024 * 1024;
    __shared__ u16 tile[32][33];
    int tx = threadIdx.x, ty = threadIdx.y;
    int bx = blockIdx.x * 32, by = blockIdx.y * 32;
    tile[ty][tx] = f2bf(W[(size_t)(by + ty) * 1024 + bx + tx]);
    __syncthreads();
    Wt[(size_t)(bx + ty) * 1024 + by + tx] = tile[tx][ty];
}

// ---------------------------------------------------------------------------
// GEMM core (m97 structure): C[BMxN tile] = A(bf16) @ Bt(bf16)^T, + bias, *scale.
// Block tile: (MI*32) x 128, BK=32, global_load_lds width-16 staging.
// MODE 0: C[row*1024+col] fp32(OUTF32) or bf16
// MODE 1: head-split [B,H,S,64] bf16
// MODE 2: head-split TRANSPOSED [B,H,64,S] bf16 via LDS-transposed coalesced
//         epilogue (MI must be 4)
// smem: >= max(MI*32*32 + 128*32, 64*136) u16
// ---------------------------------------------------------------------------
template <int MODE, int OUTF32, int MI>
static __device__ __forceinline__ void gemm_core(u16* __restrict__ smem,
                                                 const u16* __restrict__ A,
                                                 const u16* __restrict__ Bt,
                                                 const float* __restrict__ bias,
                                                 float scale,
                                                 void* __restrict__ C,
                                                 int m0, int n0) {
    u16* As = smem;                  // (MI*32) x 32
    u16* Bs = smem + MI * 32 * 32;   // 128 x 32
    int tid  = threadIdx.x;
    int wave = tid >> 6, lane = tid & 63;
    int quad = lane >> 4, l15 = lane & 15;
    int wm = (wave & 1) * (MI * 16);
    int wn = (wave >> 1) * 64;

    floatx4 acc[MI][4] = {};

    for (int k0 = 0; k0 < 1024; k0 += 32) {
#pragma unroll
        for (int t = 0; t < MI / 2; ++t) {
            int a = t * 256 + tid;
            gload_lds16(A + (size_t)(m0 + (a >> 2)) * 1024 + k0 + (a & 3) * 8, As + (size_t)a * 8);
        }
#pragma unroll
        for (int t = 0; t < 2; ++t) {
            int cb = t * 256 + tid;
            gload_lds16(Bt + (size_t)(n0 + (cb >> 2)) * 1024 + k0 + (cb & 3) * 8, Bs + (size_t)cb * 8);
        }
        __syncthreads();   // drains vmcnt before barrier

        short8 af[MI], bfr[4];
#pragma unroll
        for (int i = 0; i < MI; ++i)
            af[i] = *(const short8*)(As + (wm + i * 16 + l15) * 32 + quad * 8);
#pragma unroll
        for (int j = 0; j < 4; ++j)
            bfr[j] = *(const short8*)(Bs + (wn + j * 16 + l15) * 32 + quad * 8);
#pragma unroll
        for (int i = 0; i < MI; ++i)
#pragma unroll
            for (int j = 0; j < 4; ++j)
                acc[i][j] = __builtin_amdgcn_mfma_f32_16x16x32_bf16(af[i], bfr[j], acc[i][j], 0, 0, 0);
        __syncthreads();
    }

    if constexpr (MODE == 2) {
        // Transposed epilogue: two 64-col passes through LDS T[64][136], then
        // coalesced 256B row-bursts to V^T [B,H,64,S].
        u16* T = smem;   // 64*136 u16, aliases As/Bs (dead now)
        int bb = m0 >> 11;
#pragma unroll
        for (int p = 0; p < 2; ++p) {
            if (p) __syncthreads();          // prior copy reads complete
            if ((wave >> 1) == p) {
#pragma unroll
                for (int j = 0; j < 4; ++j) {
                    int dcol = j * 16 + l15;                 // 0..63 within pass
                    float bv = bias[n0 + p * 64 + dcol];
#pragma unroll
                    for (int i = 0; i < MI; ++i) {
#pragma unroll
                        for (int rr = 0; rr < 2; ++rr) {
                            int srow = wm + i * 16 + quad * 4 + rr * 2;
                            u16 lo = f2bf((acc[i][j][rr * 2]     + bv) * scale);
                            u16 hi = f2bf((acc[i][j][rr * 2 + 1] + bv) * scale);
                            *(u32*)(T + dcol * 136 + srow) = (u32)lo | ((u32)hi << 16);
                        }
                    }
                }
            }
            __syncthreads();                 // T visible to all
            int d  = tid >> 2;               // 0..63
            int sc = (tid & 3) * 32;
            int col = n0 + p * 64 + d;
            int h = col >> 6, dd = col & 63;
            int s0 = (m0 & 2047) + sc;
            size_t gbase = (((size_t)bb * NHEADS + h) * HDIM + dd) * SEQ + s0;
#pragma unroll
            for (int c = 0; c < 4; ++c)
                *(short8*)((u16*)C + gbase + c * 8) = *(const short8*)(T + d * 136 + sc + c * 8);
        }
        return;
    }

    // epilogue (MODE 0/1): C/D layout col=lane&15, row=quad*4+reg
#pragma unroll
    for (int j = 0; j < 4; ++j) {
        int col = n0 + wn + j * 16 + l15;
        float bv = bias[col];
#pragma unroll
        for (int i = 0; i < MI; ++i) {
#pragma unroll
            for (int r = 0; r < 4; ++r) {
                int row = m0 + wm + i * 16 + quad * 4 + r;
                float v = (acc[i][j][r] + bv) * scale;
                size_t idx;
                if (MODE == 0) {
                    idx = (size_t)row * 1024 + col;
                } else {  // MODE 1: [B,H,S,64]
                    int b = row >> 11, s = row & 2047;
                    int h = col >> 6,  d = col & 63;
                    idx = (((size_t)b * NHEADS + h) * SEQ + s) * HDIM + d;
                }
                if constexpr (OUTF32) ((float*)C)[idx] = v;
                else                  ((u16*)C)[idx] = f2bf(v);
            }
        }
    }
}

// QKV fused: grid (8, 32, 3) = 768 blocks. Q pre-scaled by log2(e)/8; V
// written transposed. __launch_bounds__(256,3): grid is EXACTLY 3 blocks/CU,
// so residency requires VGPR<=170 — pin it (R4 post-mortem: unexplained
// ~60us in support kernels; unconstrained allocator exceeding 170 would
// leave 1/3 of the grid serialized).
__global__ __launch_bounds__(256, 3) void gemm_qkv(const u16* __restrict__ X,
                                                   const u16* __restrict__ WtBase,
                                                   const float* __restrict__ bq,
                                                   const float* __restrict__ bk,
                                                   const float* __restrict__ bv,
                                                   u16* __restrict__ OutBase) {
    __shared__ __align__(16) u16 smem[8704];   // max(As+Bs=8192, T=64*136=8704)
    int z = blockIdx.z;
    const u16* Bt     = WtBase + (size_t)z * 1024 * 1024;
    const float* bias = (z == 0) ? bq : (z == 1) ? bk : bv;
    u16* C            = OutBase + (size_t)z * (size_t)M_TOK * 1024;
    if (z == 2)
        gemm_core<2, 0, 4>(smem, X, Bt, bias, 1.0f, C, blockIdx.y * 128, blockIdx.x * 128);
    else if (z == 0)
        gemm_core<1, 0, 4>(smem, X, Bt, bias, 0.18033688011112042f /* log2(e)/8 */, C,
                           blockIdx.y * 128, blockIdx.x * 128);
    else
        gemm_core<1, 0, 4>(smem, X, Bt, bias, 1.0f, C, blockIdx.y * 128, blockIdx.x * 128);
}

// Output projection: grid (8, 64), 64x128 tiles -> 512 blocks (2/CU). fp32 out.
__global__ __launch_bounds__(256, 2) void gemm_out(const u16* __restrict__ A,
                                                   const u16* __restrict__ Bt,
                                                   const float* __restrict__ bias,
                                                   float* __restrict__ C) {
    __shared__ __align__(16) u16 smem[6144];   // As 64x32 + Bs 128x32
    gemm_core<0, 1, 2>(smem, A, Bt, bias, 1.0f, C, blockIdx.y * 64, blockIdx.x * 128);
}

// ---------------------------------------------------------------------------
// Flash attention v10. grid (SEQ/128, BATCH*NHEADS), 512 threads (8 waves).
// v9 (K staged in LDS once/block, dbuf DMA) + MFMA row-sums:
// - R4 counters: MfmaUtil 20%, VALUBusy 52% -> VALU is now the top consumer.
//   The 32 v_add_f32/iter lrow accumulation (serial chain inside the exp
//   loop) is replaced by ONE extra MFMA per 32-kv chunk against a constant
//   ones B-frag: o_sum = mfma(pf, ones, o_sum). D[m=q][n]=rowsum(P), same
//   layout as o -> epilogue needs NO shuffles (o_sum[r] is already the sum
//   for q=quad*4+r in every lane). 4 MFMA (~20cyc) replaces ~64 VALU cyc
//   and shortens the exp->pack dependency chain.
// - Denominator now sums bf16-quantized P — consistent with the PV numerator.
// Everything else identical to v9.
// ---------------------------------------------------------------------------
#define PST2 40
__global__ __launch_bounds__(512, 3) void attn_k(const u16* __restrict__ Q,
                                                 const u16* __restrict__ K,
                                                 const u16* __restrict__ Vt_g,
                                                 u16* __restrict__ O) {
    __shared__ __align__(16) u16 Vt[2][64 * 128];   // V^T tile, swizzled granules, 2x16KB
    __shared__ __align__(16) u16 Kt[2][128 * 64];   // K tile, swizzled granules, 2x16KB
    __shared__ __align__(16) u16 Pl[8][16 * PST2];  // per-wave P chunk, 10240 B

    int tid  = threadIdx.x;
    int wave = tid >> 6, lane = tid & 63;
    int quad = lane >> 4, l15 = lane & 15;
    int bh = blockIdx.y;
    int b = bh >> 4, h = bh & 15;
    const u16* Qb = Q    + (size_t)bh * SEQ * HDIM;
    const u16* Kb = K    + (size_t)bh * SEQ * HDIM;
    const u16* Vb = Vt_g + (size_t)bh * HDIM * SEQ;   // [d][s]
    int q0 = blockIdx.x * 128 + wave * 16;

    // Q A/B-frags (pre-scaled): [m=l15][k=quad*8+j]
    short8 qf0 = *(const short8*)(Qb + (size_t)(q0 + l15) * 64 + quad * 8);
    short8 qf1 = *(const short8*)(Qb + (size_t)(q0 + l15) * 64 + 32 + quad * 8);

    // constant ones B-frag (bf16 1.0 = 0x3F80) for MFMA row-sums
    short8 onesf;
#pragma unroll
    for (int i = 0; i < 8; ++i) onesf[i] = (short)0x3F80;

    floatx4 o[4] = {};
    floatx4 o_sum = {};   // row-sums of P, same D-layout as o (row=q, cols dup)

    // DMA K+V tile 0 into buffer 0 (each 1024 granules / 512 threads = 2 rounds)
    {
#pragma unroll
        for (int rnd = 0; rnd < 2; ++rnd) {
            int g = rnd * 512 + tid;
            int vrow = g >> 4, vc = g & 15;
            gload_lds16(Vb + (size_t)vrow * SEQ + (vc ^ (vrow & 15)) * 8,
                        Vt[0] + (size_t)g * 8);
            int krow = g >> 3, kc = g & 7;
            gload_lds16(Kb + (size_t)krow * 64 + (kc ^ (krow & 7)) * 8,
                        Kt[0] + (size_t)g * 8);
        }
    }

    for (int it = 0; it < SEQ / 128; ++it) {
        int kv0 = it * 128;
        __syncthreads();   // drains DMA(it) [issued one iter ago]

        // --- issue K+V DMA(it+1) into the other buffer ---
        if (it + 1 < SEQ / 128) {
            u16* vdst = Vt[(it + 1) & 1];
            u16* kdst = Kt[(it + 1) & 1];
#pragma unroll
            for (int rnd = 0; rnd < 2; ++rnd) {
                int g = rnd * 512 + tid;
                int vrow = g >> 4, vc = g & 15;
                gload_lds16(Vb + (size_t)vrow * SEQ + kv0 + 128 + (vc ^ (vrow & 15)) * 8,
                            vdst + (size_t)g * 8);
                int krow = g >> 3, kc = g & 7;
                gload_lds16(Kb + (size_t)(kv0 + 128 + krow) * 64 + (kc ^ (krow & 7)) * 8,
                            kdst + (size_t)g * 8);
            }
        }

        // --- S^T = K @ Q^T, K frags from LDS (swizzled read) ---
        // s[j] layout: col=l15 = q, row=quad*4+r = kv within j-block
        const u16* kb = Kt[it & 1];
        floatx4 s[8];
        __builtin_amdgcn_s_setprio(1);
#pragma unroll
        for (int j = 0; j < 8; ++j) {
            int row = j * 16 + l15;                    // row&7 == l15&7
            const u16* kr = kb + (size_t)row * 64;
            short8 k0 = *(const short8*)(kr + ((quad ^ (l15 & 7)) * 8));
            short8 k1 = *(const short8*)(kr + (((quad + 4) ^ (l15 & 7)) * 8));
            floatx4 a = {};
            a = __builtin_amdgcn_mfma_f32_16x16x32_bf16(k0, qf0, a, 0, 0, 0);
            a = __builtin_amdgcn_mfma_f32_16x16x32_bf16(k1, qf1, a, 0, 0, 0);
            s[j] = a;
        }
        __builtin_amdgcn_s_setprio(0);

        // --- per-32-kv chunk: p = exp2(s), pack+store P, then PV on that chunk ---
        const u16* vb = Vt[it & 1];
#pragma unroll
        for (int kh = 0; kh < 4; ++kh) {
            // produce P chunk kh (kv = kh*32 .. kh*32+31), q = l15
#pragma unroll
            for (int t = 0; t < 2; ++t) {
                int j = kh * 2 + t;
                float p0 = exp2f(s[j][0]), p1 = exp2f(s[j][1]);
                float p2 = exp2f(s[j][2]), p3 = exp2f(s[j][3]);
                u32 w0 = cvtpk(p0, p1), w1 = cvtpk(p2, p3);
                // kv' = t*16 + quad*4 + r  (4 contiguous bf16 -> one b64)
                *(u32x2*)(&Pl[wave][l15 * PST2 + t * 16 + quad * 4]) = (u32x2){w0, w1};
            }
            // consume: A-frag P[m=l15=q][k=quad*8+i]
            short8 pf = *(const short8*)(&Pl[wave][l15 * PST2 + quad * 8]);
            __builtin_amdgcn_s_setprio(1);
#pragma unroll
            for (int dj = 0; dj < 4; ++dj) {
                int row = dj * 16 + l15;
                int cg  = kh * 4 + quad;
                short8 vf = *(const short8*)(&vb[(row * 16 + (cg ^ l15)) * 8]);
                o[dj] = __builtin_amdgcn_mfma_f32_16x16x32_bf16(pf, vf, o[dj], 0, 0, 0);
            }
            // row-sum via ones B-frag: o_sum[r] += sum_k P[q=quad*4+r][k]
            o_sum = __builtin_amdgcn_mfma_f32_16x16x32_bf16(pf, onesf, o_sum, 0, 0, 0);
            __builtin_amdgcn_s_setprio(0);
        }
    }

    // --- epilogue: o_sum[r] is the full row sum for q=quad*4+r (all lanes) ---
#pragma unroll
    for (int r = 0; r < 4; ++r) {
        float invq = 1.f / o_sum[r];
        int srow = q0 + quad * 4 + r;
        size_t base = ((size_t)b * SEQ + srow) * D_MODEL + h * HDIM;
#pragma unroll
        for (int dj = 0; dj < 4; ++dj)
            O[base + dj * 16 + l15] = f2bf(o[dj][r] * invq);
    }
}

// ---------------------------------------------------------------------------
extern "C" void kernel_launch(void* const* d_in, const int* in_sizes, int n_in,
                              void* d_out, int out_size, void* d_ws, size_t ws_size,
                              hipStream_t stream) {
    const float* x  = (const float*)d_in[0];
    const float* Wq = (const float*)d_in[1];
    const float* bq = (const float*)d_in[2];
    const float* Wk = (const float*)d_in[3];
    const float* bk = (const float*)d_in[4];
    const float* Wv = (const float*)d_in[5];
    const float* bv = (const float*)d_in[6];
    const float* Wo = (const float*)d_in[7];
    const float* bo = (const float*)d_in[8];
    float* out = (float*)d_out;

    char* ws = (char*)d_ws;
    const size_t WSZ = (size_t)1024 * 1024 * sizeof(u16);   // 2MB per bf16 weight
    const size_t QSZ = (size_t)M_TOK * 1024 * sizeof(u16);  // 8MB per bf16 activation
    const size_t NEED = 4 * WSZ + 4 * QSZ;                  // 40MB

    if (ws_size < NEED) {
        zerofill_k<<<dim3((out_size + 255) / 256), 256, 0, stream>>>(out, out_size);
        return;
    }

    u16* wtq = (u16*)(ws);                       // wt q,k,v,o contiguous
    u16* wto = (u16*)(ws + 3 * WSZ);
    u16* Qw  = (u16*)(ws + 4 * WSZ);             // Q,K [B,H,S,64]; V^T [B,H,64,S]
    u16* Kw  = (u16*)(ws + 4 * WSZ + QSZ);
    u16* Vw  = (u16*)(ws + 4 * WSZ + 2 * QSZ);
    u16* Xb  = (u16*)(ws + 4 * WSZ + 3 * QSZ);   // x bf16; dead after gemm_qkv
    u16* Aw  = Xb;                               // attention output reuses Xb

    prep_k<<<dim3(32, 32, 5), dim3(32, 32), 0, stream>>>(x, Wq, Wk, Wv, Wo, wtq, Xb);

    gemm_qkv<<<dim3(8, 32, 3), 256, 0, stream>>>(Xb, wtq, bq, bk, bv, Qw);
    attn_k<<<dim3(SEQ / 128, BATCH * NHEADS), 512, 0, stream>>>(Qw, Kw, Vw, Aw);
    gemm_out<<<dim3(8, 64), 256, 0, stream>>>(Aw, wto, bo, out);
}